// Round 1
// baseline (3888.638 us; speedup 1.0000x reference)
//
#include <hip/hip_runtime.h>
#include <math.h>

#define NK 27
#define C1 128
#define C2 14
#define X1S 16   // padded row stride for intermediate (64B aligned)

// ---------------- conv1: (N,128) gather @ W1[k](128,14) -> scatter-add x1 ----------------
__global__ __launch_bounds__(256) void conv1_kernel(
    const float* __restrict__ feat, const float* __restrict__ W1,
    const int* __restrict__ in_idx, const int* __restrict__ out_idx,
    float* __restrict__ x1, int N)
{
    __shared__ float Wl[C2 * C1];   // transposed: Wl[c*128 + i] = W1[k][i][c]
    const int k   = blockIdx.y;
    const int tid = threadIdx.x;

    for (int t = tid; t < C2 * C1; t += 256) {
        int c = t >> 7;        // t / 128
        int i = t & 127;       // t % 128
        Wl[t] = W1[k * (C1 * C2) + i * C2 + c];
    }
    __syncthreads();

    const int jbase = (blockIdx.x * 256 + tid) * 4;
    if (jbase >= N) return;

    int src[4], dst[4];
    if (jbase + 3 < N) {
        const int4 si = *(const int4*)(in_idx  + (size_t)k * N + jbase);
        const int4 di = *(const int4*)(out_idx + (size_t)k * N + jbase);
        src[0] = si.x; src[1] = si.y; src[2] = si.z; src[3] = si.w;
        dst[0] = di.x; dst[1] = di.y; dst[2] = di.z; dst[3] = di.w;
    } else {
        for (int p = 0; p < 4; ++p) {
            int j = jbase + p;
            src[p] = (j < N) ? in_idx[(size_t)k * N + j]  : N;
            dst[p] = (j < N) ? out_idx[(size_t)k * N + j] : N;
        }
    }

    bool valid[4];
    bool any = false;
    #pragma unroll
    for (int p = 0; p < 4; ++p) {
        valid[p] = (dst[p] < N);
        any |= valid[p];
        if (!valid[p]) src[p] = 0;   // safe dummy row; result discarded
    }
    if (!any) return;   // padded suffix region — whole wave exits fast

    const float4* fa = (const float4*)(feat + (size_t)src[0] * C1);
    const float4* fb = (const float4*)(feat + (size_t)src[1] * C1);
    const float4* fc = (const float4*)(feat + (size_t)src[2] * C1);
    const float4* fd = (const float4*)(feat + (size_t)src[3] * C1);

    float acc[4][C2];
    #pragma unroll
    for (int p = 0; p < 4; ++p)
        #pragma unroll
        for (int c = 0; c < C2; ++c) acc[p][c] = 0.f;

    for (int i4 = 0; i4 < C1 / 4; ++i4) {
        float4 a = fa[i4];
        float4 b = fb[i4];
        float4 cc = fc[i4];
        float4 d = fd[i4];
        #pragma unroll
        for (int c = 0; c < C2; ++c) {
            float4 w = *(const float4*)&Wl[c * C1 + i4 * 4];
            acc[0][c] = fmaf(a.x,  w.x, fmaf(a.y,  w.y, fmaf(a.z,  w.z, fmaf(a.w,  w.w, acc[0][c]))));
            acc[1][c] = fmaf(b.x,  w.x, fmaf(b.y,  w.y, fmaf(b.z,  w.z, fmaf(b.w,  w.w, acc[1][c]))));
            acc[2][c] = fmaf(cc.x, w.x, fmaf(cc.y, w.y, fmaf(cc.z, w.z, fmaf(cc.w, w.w, acc[2][c]))));
            acc[3][c] = fmaf(d.x,  w.x, fmaf(d.y,  w.y, fmaf(d.z,  w.z, fmaf(d.w,  w.w, acc[3][c]))));
        }
    }

    #pragma unroll
    for (int p = 0; p < 4; ++p) {
        if (!valid[p]) continue;
        float* o = x1 + (size_t)dst[p] * X1S;
        #pragma unroll
        for (int c = 0; c < C2; ++c) atomicAdd(o + c, acc[p][c]);
    }
}

// ---------------- exact GELU, in-place on x1 (padded lanes are 0 -> gelu(0)=0) ----------------
__global__ __launch_bounds__(256) void gelu_kernel(float* __restrict__ x, int total4)
{
    int i = blockIdx.x * 256 + threadIdx.x;
    if (i >= total4) return;
    float4 v = ((float4*)x)[i];
    v.x = 0.5f * v.x * (1.0f + erff(v.x * 0.70710678118654752f));
    v.y = 0.5f * v.y * (1.0f + erff(v.y * 0.70710678118654752f));
    v.z = 0.5f * v.z * (1.0f + erff(v.z * 0.70710678118654752f));
    v.w = 0.5f * v.w * (1.0f + erff(v.w * 0.70710678118654752f));
    ((float4*)x)[i] = v;
}

// ---------------- conv2: (N,14) gather @ W2[k](14,14) -> scatter-add out(N,14) ----------------
__global__ __launch_bounds__(256) void conv2_kernel(
    const float* __restrict__ x1, const float* __restrict__ W2,
    const int* __restrict__ in_idx, const int* __restrict__ out_idx,
    float* __restrict__ out, int N)
{
    __shared__ float Wl[C2 * 16];   // transposed, padded: Wl[c*16 + i] = W2[k][i][c]
    const int k   = blockIdx.y;
    const int tid = threadIdx.x;

    if (tid < C2 * C2) {
        int c = tid / C2;
        int i = tid % C2;
        Wl[c * 16 + i] = W2[k * (C2 * C2) + i * C2 + c];
    }
    __syncthreads();

    const int jbase = (blockIdx.x * 256 + tid) * 2;
    if (jbase >= N) return;

    int src[2], dst[2];
    if (jbase + 1 < N) {
        const int2 si = *(const int2*)(in_idx  + (size_t)k * N + jbase);
        const int2 di = *(const int2*)(out_idx + (size_t)k * N + jbase);
        src[0] = si.x; src[1] = si.y;
        dst[0] = di.x; dst[1] = di.y;
    } else {
        src[0] = in_idx[(size_t)k * N + jbase];
        dst[0] = out_idx[(size_t)k * N + jbase];
        src[1] = N; dst[1] = N;
    }

    bool valid[2] = { dst[0] < N, dst[1] < N };
    if (!valid[0] && !valid[1]) return;

    float f[2][C2];
    #pragma unroll
    for (int p = 0; p < 2; ++p) {
        if (valid[p]) {
            const float* r = x1 + (size_t)src[p] * X1S;
            float4 q0 = *(const float4*)(r + 0);
            float4 q1 = *(const float4*)(r + 4);
            float4 q2 = *(const float4*)(r + 8);
            float2 q3 = *(const float2*)(r + 12);
            f[p][0]=q0.x; f[p][1]=q0.y; f[p][2]=q0.z; f[p][3]=q0.w;
            f[p][4]=q1.x; f[p][5]=q1.y; f[p][6]=q1.z; f[p][7]=q1.w;
            f[p][8]=q2.x; f[p][9]=q2.y; f[p][10]=q2.z; f[p][11]=q2.w;
            f[p][12]=q3.x; f[p][13]=q3.y;
        } else {
            #pragma unroll
            for (int i = 0; i < C2; ++i) f[p][i] = 0.f;
        }
    }

    float acc[2][C2];
    #pragma unroll
    for (int c = 0; c < C2; ++c) {
        float s0 = 0.f, s1 = 0.f;
        #pragma unroll
        for (int i = 0; i < C2; ++i) {
            float w = Wl[c * 16 + i];
            s0 = fmaf(f[0][i], w, s0);
            s1 = fmaf(f[1][i], w, s1);
        }
        acc[0][c] = s0;
        acc[1][c] = s1;
    }

    #pragma unroll
    for (int p = 0; p < 2; ++p) {
        if (!valid[p]) continue;
        float* o = out + (size_t)dst[p] * C2;
        #pragma unroll
        for (int c = 0; c < C2; ++c) atomicAdd(o + c, acc[p][c]);
    }
}

extern "C" void kernel_launch(void* const* d_in, const int* in_sizes, int n_in,
                              void* d_out, int out_size, void* d_ws, size_t ws_size,
                              hipStream_t stream)
{
    const float* feat    = (const float*)d_in[0];
    const float* W1      = (const float*)d_in[1];
    const float* W2      = (const float*)d_in[2];
    const int*   in_idx  = (const int*)d_in[3];
    const int*   out_idx = (const int*)d_in[4];
    float*       out     = (float*)d_out;

    const int N = in_sizes[0] / C1;      // 400000

    float* x1 = (float*)d_ws;            // N x 16 fp32 = 25.6 MB

    hipMemsetAsync(x1, 0, (size_t)N * X1S * sizeof(float), stream);
    hipMemsetAsync(out, 0, (size_t)out_size * sizeof(float), stream);

    {
        dim3 grid((N + 1023) / 1024, NK);
        conv1_kernel<<<grid, 256, 0, stream>>>(feat, W1, in_idx, out_idx, x1, N);
    }
    {
        int total4 = N * X1S / 4;
        gelu_kernel<<<(total4 + 255) / 256, 256, 0, stream>>>(x1, total4);
    }
    {
        dim3 grid((N + 511) / 512, NK);
        conv2_kernel<<<grid, 256, 0, stream>>>(x1, W2, in_idx, out_idx, out, N);
    }
}